// Round 3
// baseline (125.073 us; speedup 1.0000x reference)
//
#include <hip/hip_runtime.h>
#include <math.h>

#define D_DIM   128
#define NCHART  64
#define PADR    132      // padded row stride (floats); 132*4B = 16B-aligned rows
#define MAXNORM 0.99f

typedef float f32x4 __attribute__((ext_vector_type(4)));

__device__ __forceinline__ float wave_sum(float v) {
#pragma unroll
  for (int m = 32; m > 0; m >>= 1) v += __shfl_xor(v, m, 64);
  return v;
}

// ---------------- stage 1: z_global = mobius(-proj(c_src), proj(z)); v = R_tgt @ z_global
__global__ __launch_bounds__(256) void k_stage1(
    const float* __restrict__ z_n, const float* __restrict__ centers,
    const float* __restrict__ rot, const int* __restrict__ src_idx,
    const int* __restrict__ tgt_idx, float* __restrict__ vout, int B)
{
  __shared__ float R[D_DIM * PADR];   // ~67.6 KB
  __shared__ float zs[4][D_DIM];      // per-wave broadcast buffer

  const int tid = threadIdx.x;
  const int chart = blockIdx.x >> 2;  // 4 blocks per chart
  const int q = blockIdx.x & 3;

  // stage R[chart] into padded LDS (coalesced b128 reads, aligned b128 writes)
  const f32x4* G4 = (const f32x4*)(rot + (size_t)chart * D_DIM * D_DIM);
  for (int g = tid; g < 4096; g += 256) {
    int r = g >> 5, J = g & 31;
    *(f32x4*)&R[r * PADR + 4 * J] = G4[g];
  }
  __syncthreads();

  const int w = tid >> 6, l = tid & 63;
  const int gw = q * 4 + w;           // global wave id within chart group, 0..15

  for (int b = gw; b < B; b += 16) {
    if (tgt_idx[b] != chart) continue;          // wave-uniform branch

    // lane l owns elements l and l+64 of the row
    float a  = z_n[(size_t)b * D_DIM + l];
    float bb = z_n[(size_t)b * D_DIM + l + 64];
    float nz = sqrtf(wave_sum(a * a + bb * bb));
    if (nz > MAXNORM) { float s = MAXNORM / nz; a *= s; bb *= s; }

    int si = src_idx[b];
    float c0 = centers[(size_t)si * D_DIM + l];
    float c1 = centers[(size_t)si * D_DIM + l + 64];
    float ncn = sqrtf(wave_sum(c0 * c0 + c1 * c1));
    if (ncn > MAXNORM) { float s = MAXNORM / ncn; c0 *= s; c1 *= s; }
    c0 = -c0; c1 = -c1;                          // x = -c_source

    float x2 = wave_sum(c0 * c0 + c1 * c1);
    float y2 = wave_sum(a * a + bb * bb);
    float xy = wave_sum(c0 * a + c1 * bb);
    float nx  = 1.0f + 2.0f * xy + y2;           // coeff of x   (c = 1)
    float ny  = 1.0f - x2;                       // coeff of y
    float inv = 1.0f / fmaxf(1.0f + 2.0f * xy + x2 * y2, 1e-15f);
    float zg0 = (nx * c0 + ny * a)  * inv;
    float zg1 = (nx * c1 + ny * bb) * inv;

    // broadcast z_global through LDS
    zs[w][l] = zg0; zs[w][l + 64] = zg1;
    asm volatile("s_waitcnt lgkmcnt(0)" ::: "memory");

    // v_i = sum_j R[i][j] z_j ; lane owns rows l and l+64
    float acc0 = 0.0f, acc1 = 0.0f;
#pragma unroll
    for (int Jg = 0; Jg < 32; ++Jg) {
      f32x4 a0 = *(const f32x4*)&R[l * PADR + 4 * Jg];
      f32x4 a1 = *(const f32x4*)&R[(l + 64) * PADR + 4 * Jg];
      f32x4 zv = *(const f32x4*)&zs[w][4 * Jg];  // uniform address = broadcast
#pragma unroll
      for (int m = 0; m < 4; ++m) {
        acc0 = fmaf(a0[m], zv[m], acc0);
        acc1 = fmaf(a1[m], zv[m], acc1);
      }
    }
    vout[(size_t)b * D_DIM + l]      = acc0;
    vout[(size_t)b * D_DIM + l + 64] = acc1;
  }
}

// ---------------- stage 2: w = R_src^T @ v; out = proj(mobius(proj(c_tgt), w))
__global__ __launch_bounds__(256) void k_stage2(
    const float* __restrict__ centers, const float* __restrict__ rot,
    const int* __restrict__ src_idx, const int* __restrict__ tgt_idx,
    float* __restrict__ io, int B)
{
  __shared__ float R[D_DIM * PADR];
  __shared__ float vs[4][D_DIM];

  const int tid = threadIdx.x;
  const int chart = blockIdx.x >> 2;
  const int q = blockIdx.x & 3;

  const f32x4* G4 = (const f32x4*)(rot + (size_t)chart * D_DIM * D_DIM);
  for (int g = tid; g < 4096; g += 256) {
    int r = g >> 5, J = g & 31;
    *(f32x4*)&R[r * PADR + 4 * J] = G4[g];
  }
  __syncthreads();

  const int w = tid >> 6, l = tid & 63;
  const int gw = q * 4 + w;

  for (int b = gw; b < B; b += 16) {
    if (src_idx[b] != chart) continue;

    float v0 = io[(size_t)b * D_DIM + l];
    float v1 = io[(size_t)b * D_DIM + l + 64];
    vs[w][l] = v0; vs[w][l + 64] = v1;
    asm volatile("s_waitcnt lgkmcnt(0)" ::: "memory");

    // w_i = sum_j R[j][i] v_j ; column reads: bank (4j+l)%32 -> 2 lanes/bank (free)
    float acc0 = 0.0f, acc1 = 0.0f;
#pragma unroll 8
    for (int j = 0; j < 128; ++j) {
      float r0 = R[j * PADR + l];
      float r1 = R[j * PADR + l + 64];
      float vj = vs[w][j];                       // uniform address = broadcast
      acc0 = fmaf(r0, vj, acc0);
      acc1 = fmaf(r1, vj, acc1);
    }

    int ti = tgt_idx[b];
    float c0 = centers[(size_t)ti * D_DIM + l];
    float c1 = centers[(size_t)ti * D_DIM + l + 64];
    float ncn = sqrtf(wave_sum(c0 * c0 + c1 * c1));
    if (ncn > MAXNORM) { float s = MAXNORM / ncn; c0 *= s; c1 *= s; }

    float x2 = wave_sum(c0 * c0 + c1 * c1);
    float y2 = wave_sum(acc0 * acc0 + acc1 * acc1);
    float xy = wave_sum(c0 * acc0 + c1 * acc1);
    float nx  = 1.0f + 2.0f * xy + y2;
    float ny  = 1.0f - x2;
    float inv = 1.0f / fmaxf(1.0f + 2.0f * xy + x2 * y2, 1e-15f);
    float o0 = (nx * c0 + ny * acc0) * inv;
    float o1 = (nx * c1 + ny * acc1) * inv;

    float no = sqrtf(wave_sum(o0 * o0 + o1 * o1));
    if (no > MAXNORM) { float s = MAXNORM / no; o0 *= s; o1 *= s; }

    io[(size_t)b * D_DIM + l]      = o0;
    io[(size_t)b * D_DIM + l + 64] = o1;
  }
}

extern "C" void kernel_launch(void* const* d_in, const int* in_sizes, int n_in,
                              void* d_out, int out_size, void* d_ws, size_t ws_size,
                              hipStream_t stream) {
  const float* z_n     = (const float*)d_in[0];
  const float* centers = (const float*)d_in[1];
  const float* rot     = (const float*)d_in[2];
  const int*   src     = (const int*)d_in[3];
  const int*   tgt     = (const int*)d_in[4];
  float* out = (float*)d_out;
  const int B = in_sizes[3];

  dim3 grid(NCHART * 4), block(256);
  k_stage1<<<grid, block, 0, stream>>>(z_n, centers, rot, src, tgt, out, B);
  k_stage2<<<grid, block, 0, stream>>>(centers, rot, src, tgt, out, B);
}

// Round 5
// 55.040 us; speedup vs baseline: 2.2724x; 2.2724x over previous
//
#include <hip/hip_runtime.h>
#include <math.h>

#define D_DIM   128
#define NCHART  64
#define PADR    132      // padded row stride (floats); 132*4B = 16B-aligned rows
#define BPC     8        // blocks per chart (512 blocks = 2/CU at 69.6KB LDS)
#define MAXNORM 0.99f

typedef float f32x4 __attribute__((ext_vector_type(4)));

__device__ __forceinline__ float wave_sum(float v) {
#pragma unroll
  for (int m = 32; m > 0; m >>= 1) v += __shfl_xor(v, m, 64);
  return v;
}

// ws layout (ints): [0..63] tgt_off | [64..127] tgt_cnt | [128..191] src_off |
//                   [192..255] src_cnt | [256..256+B) tgt_list | [256+B..256+2B) src_list
__global__ __launch_bounds__(256) void k_setup(
    const int* __restrict__ src, const int* __restrict__ tgt,
    int* __restrict__ ws, int B)
{
  __shared__ int cntT[NCHART], cntS[NCHART], offT[NCHART], offS[NCHART];
  const int tid = threadIdx.x;
  if (tid < NCHART) { cntT[tid] = 0; cntS[tid] = 0; }
  __syncthreads();
  for (int b = tid; b < B; b += 256) {
    atomicAdd(&cntT[tgt[b]], 1);
    atomicAdd(&cntS[src[b]], 1);
  }
  __syncthreads();
  if (tid == 0) {
    int aT = 0, aS = 0;
    for (int c = 0; c < NCHART; ++c) {
      offT[c] = aT; aT += cntT[c];
      offS[c] = aS; aS += cntS[c];
    }
  }
  __syncthreads();
  if (tid < NCHART) {
    ws[tid]            = offT[tid];
    ws[NCHART + tid]   = cntT[tid];
    ws[2*NCHART + tid] = offS[tid];
    ws[3*NCHART + tid] = cntS[tid];
  }
  if (tid < NCHART) { cntT[tid] = 0; cntS[tid] = 0; }
  __syncthreads();
  int* tlist = ws + 4*NCHART;
  int* slist = tlist + B;
  for (int b = tid; b < B; b += 256) {
    int ct = tgt[b]; int p = atomicAdd(&cntT[ct], 1); tlist[offT[ct] + p] = b;
    int cs = src[b]; int r = atomicAdd(&cntS[cs], 1); slist[offS[cs] + r] = b;
  }
}

// ---------------- stage 1: z_global = mobius(-proj(c_src), proj(z)); v = R_tgt @ z_global
__global__ __launch_bounds__(256) void k_stage1(
    const float* __restrict__ z_n, const float* __restrict__ centers,
    const float* __restrict__ rot, const int* __restrict__ src_idx,
    const int* __restrict__ ws, float* __restrict__ vout)
{
  __shared__ float R[D_DIM * PADR];   // ~67.6 KB
  __shared__ float zs[4][D_DIM];

  const int tid = threadIdx.x;
  const int chart = blockIdx.x >> 3;
  const int q = blockIdx.x & 7;
  const int n = ws[NCHART + chart];
  if (4 * q >= n) return;             // block-uniform early exit
  const int base = ws[chart];
  const int* __restrict__ tlist = ws + 4*NCHART;

  const f32x4* G4 = (const f32x4*)(rot + (size_t)chart * D_DIM * D_DIM);
  for (int g = tid; g < 4096; g += 256) {
    int r = g >> 5, J = g & 31;
    *(f32x4*)&R[r * PADR + 4 * J] = G4[g];
  }
  __syncthreads();

  const int w = tid >> 6, l = tid & 63;

  for (int s = 4 * q + w; s < n; s += 32) {
    int b = tlist[base + s];

    float a  = z_n[(size_t)b * D_DIM + l];
    float bb = z_n[(size_t)b * D_DIM + l + 64];
    float nz = sqrtf(wave_sum(a * a + bb * bb));
    if (nz > MAXNORM) { float sc = MAXNORM / nz; a *= sc; bb *= sc; }

    int si = src_idx[b];
    float c0 = centers[(size_t)si * D_DIM + l];
    float c1 = centers[(size_t)si * D_DIM + l + 64];
    float ncn = sqrtf(wave_sum(c0 * c0 + c1 * c1));
    if (ncn > MAXNORM) { float sc = MAXNORM / ncn; c0 *= sc; c1 *= sc; }
    c0 = -c0; c1 = -c1;                          // x = -c_source

    float x2 = wave_sum(c0 * c0 + c1 * c1);
    float y2 = wave_sum(a * a + bb * bb);
    float xy = wave_sum(c0 * a + c1 * bb);
    float nx  = 1.0f + 2.0f * xy + y2;
    float ny  = 1.0f - x2;
    float inv = 1.0f / fmaxf(1.0f + 2.0f * xy + x2 * y2, 1e-15f);
    float zg0 = (nx * c0 + ny * a)  * inv;
    float zg1 = (nx * c1 + ny * bb) * inv;

    zs[w][l] = zg0; zs[w][l + 64] = zg1;
    asm volatile("s_waitcnt lgkmcnt(0)" ::: "memory");

    float acc0 = 0.0f, acc1 = 0.0f;
#pragma unroll
    for (int Jg = 0; Jg < 32; ++Jg) {
      f32x4 a0 = *(const f32x4*)&R[l * PADR + 4 * Jg];
      f32x4 a1 = *(const f32x4*)&R[(l + 64) * PADR + 4 * Jg];
      f32x4 zv = *(const f32x4*)&zs[w][4 * Jg];
#pragma unroll
      for (int m = 0; m < 4; ++m) {
        acc0 = fmaf(a0[m], zv[m], acc0);
        acc1 = fmaf(a1[m], zv[m], acc1);
      }
    }
    vout[(size_t)b * D_DIM + l]      = acc0;
    vout[(size_t)b * D_DIM + l + 64] = acc1;
  }
}

// ---------------- stage 2: w = R_src^T @ v; out = proj(mobius(proj(c_tgt), w))
__global__ __launch_bounds__(256) void k_stage2(
    const float* __restrict__ centers, const float* __restrict__ rot,
    const int* __restrict__ tgt_idx, const int* __restrict__ ws,
    float* __restrict__ io, int B)
{
  __shared__ float R[D_DIM * PADR];
  __shared__ float vs[4][D_DIM];

  const int tid = threadIdx.x;
  const int chart = blockIdx.x >> 3;
  const int q = blockIdx.x & 7;
  const int n = ws[3*NCHART + chart];
  if (4 * q >= n) return;
  const int base = ws[2*NCHART + chart];
  const int* __restrict__ slist = ws + 4*NCHART + B;

  const f32x4* G4 = (const f32x4*)(rot + (size_t)chart * D_DIM * D_DIM);
  for (int g = tid; g < 4096; g += 256) {
    int r = g >> 5, J = g & 31;
    *(f32x4*)&R[r * PADR + 4 * J] = G4[g];
  }
  __syncthreads();

  const int w = tid >> 6, l = tid & 63;

  for (int s = 4 * q + w; s < n; s += 32) {
    int b = slist[base + s];

    float v0 = io[(size_t)b * D_DIM + l];
    float v1 = io[(size_t)b * D_DIM + l + 64];
    vs[w][l] = v0; vs[w][l + 64] = v1;
    asm volatile("s_waitcnt lgkmcnt(0)" ::: "memory");

    // w_i = sum_j R[j][i] v_j ; column reads: bank (4j+l)%32 -> 2 lanes/bank (free)
    float acc0 = 0.0f, acc1 = 0.0f;
#pragma unroll 8
    for (int j = 0; j < 128; ++j) {
      float r0 = R[j * PADR + l];
      float r1 = R[j * PADR + l + 64];
      float vj = vs[w][j];
      acc0 = fmaf(r0, vj, acc0);
      acc1 = fmaf(r1, vj, acc1);
    }

    int ti = tgt_idx[b];
    float c0 = centers[(size_t)ti * D_DIM + l];
    float c1 = centers[(size_t)ti * D_DIM + l + 64];
    float ncn = sqrtf(wave_sum(c0 * c0 + c1 * c1));
    if (ncn > MAXNORM) { float sc = MAXNORM / ncn; c0 *= sc; c1 *= sc; }

    float x2 = wave_sum(c0 * c0 + c1 * c1);
    float y2 = wave_sum(acc0 * acc0 + acc1 * acc1);
    float xy = wave_sum(c0 * acc0 + c1 * acc1);
    float nx  = 1.0f + 2.0f * xy + y2;
    float ny  = 1.0f - x2;
    float inv = 1.0f / fmaxf(1.0f + 2.0f * xy + x2 * y2, 1e-15f);
    float o0 = (nx * c0 + ny * acc0) * inv;
    float o1 = (nx * c1 + ny * acc1) * inv;

    float no = sqrtf(wave_sum(o0 * o0 + o1 * o1));
    if (no > MAXNORM) { float sc = MAXNORM / no; o0 *= sc; o1 *= sc; }

    io[(size_t)b * D_DIM + l]      = o0;
    io[(size_t)b * D_DIM + l + 64] = o1;
  }
}

extern "C" void kernel_launch(void* const* d_in, const int* in_sizes, int n_in,
                              void* d_out, int out_size, void* d_ws, size_t ws_size,
                              hipStream_t stream) {
  const float* z_n     = (const float*)d_in[0];
  const float* centers = (const float*)d_in[1];
  const float* rot     = (const float*)d_in[2];
  const int*   src     = (const int*)d_in[3];
  const int*   tgt     = (const int*)d_in[4];
  float* out = (float*)d_out;
  int* ws = (int*)d_ws;
  const int B = in_sizes[3];

  k_setup<<<dim3(1), dim3(256), 0, stream>>>(src, tgt, ws, B);
  dim3 grid(NCHART * BPC), block(256);
  k_stage1<<<grid, block, 0, stream>>>(z_n, centers, rot, src, ws, out);
  k_stage2<<<grid, block, 0, stream>>>(centers, rot, tgt, ws, out, B);
}